// Round 1
// baseline (390.344 us; speedup 1.0000x reference)
//
#include <hip/hip_runtime.h>
#include <hip/hip_bf16.h>
#include <hip/hip_fp16.h>

typedef _Float16 half8 __attribute__((ext_vector_type(8)));
typedef _Float16 half4_t __attribute__((ext_vector_type(4)));
typedef float f32x4 __attribute__((ext_vector_type(4)));

#define NEG_SLOPE 0.2f
#define SELU_SCALE 1.0507009873554805f
#define SELU_ALPHA 1.6732632423543772f

// ---------------- GEMM: glr[n][c] = sum_k x[n][k] * Wcat[k][c], c in [0,768)
// cols 0..383 = W_l (gl), 384..767 = W_r (gr). f16 output, fp32 MFMA accum.
__global__ __launch_bounds__(256) void gemm_kernel(
    const float* __restrict__ x, const float* __restrict__ Wl,
    const float* __restrict__ Wr, _Float16* __restrict__ glr, int n_nodes)
{
    int wid  = threadIdx.x >> 6;
    int lane = threadIdx.x & 63;
    int row0 = blockIdx.x * 64 + wid * 16;
    if (row0 >= n_nodes) return;           // n_nodes % 16 == 0 assumed (50000 ok)
    int col0 = blockIdx.y * 64;
    int l15  = lane & 15;
    int kb   = (lane >> 4) * 8;

    // A fragment: A[row=l15][k = kb + j] (and +32 for second K-half)
    const float* xrow = x + (size_t)(row0 + l15) * 64;
    half8 a0, a1;
    #pragma unroll
    for (int j = 0; j < 8; j++) {
        a0[j] = (_Float16)xrow[kb + j];
        a1[j] = (_Float16)xrow[32 + kb + j];
    }
    f32x4 acc[4];
    #pragma unroll
    for (int t = 0; t < 4; t++) acc[t] = (f32x4){0.f, 0.f, 0.f, 0.f};

    #pragma unroll
    for (int t = 0; t < 4; t++) {
        int col = col0 + t * 16 + l15;
        const float* wcol = (col < 384) ? (Wl + col) : (Wr + (col - 384));
        half8 b0, b1;
        #pragma unroll
        for (int j = 0; j < 8; j++) {
            b0[j] = (_Float16)wcol[(size_t)(kb + j) * 384];
            b1[j] = (_Float16)wcol[(size_t)(32 + kb + j) * 384];
        }
        acc[t] = __builtin_amdgcn_mfma_f32_16x16x32_f16(a0, b0, acc[t], 0, 0, 0);
        acc[t] = __builtin_amdgcn_mfma_f32_16x16x32_f16(a1, b1, acc[t], 0, 0, 0);
    }
    // C layout: col = lane&15, row = (lane>>4)*4 + r   [m89-verified]
    #pragma unroll
    for (int t = 0; t < 4; t++) {
        int col = col0 + t * 16 + l15;
        #pragma unroll
        for (int r = 0; r < 4; r++) {
            int row = row0 + (lane >> 4) * 4 + r;
            glr[(size_t)row * 768 + col] = (_Float16)acc[t][r];
        }
    }
}

// ---------------- CSR build ----------------
__global__ void init_count_kernel(int* count, int n) {
    int i = blockIdx.x * blockDim.x + threadIdx.x;
    if (i < n) count[i] = 1;   // self-loop pre-counted
}

__global__ void hist_kernel(const int* __restrict__ eidx, int* count, int n_edges) {
    int i = blockIdx.x * blockDim.x + threadIdx.x;
    if (i < n_edges) atomicAdd(&count[eidx[n_edges + i]], 1);  // dst row
}

__global__ __launch_bounds__(1024) void scan_kernel(
    const int* __restrict__ count, int* __restrict__ row_ptr, int n)
{
    __shared__ int wsum[16];
    __shared__ int carry_s;
    if (threadIdx.x == 0) carry_s = 0;
    __syncthreads();
    int lane = threadIdx.x & 63;
    int wid  = threadIdx.x >> 6;
    int nchunk = (n + 1023) / 1024;
    for (int c = 0; c < nchunk; c++) {
        int i = c * 1024 + (int)threadIdx.x;
        int v = (i < n) ? count[i] : 0;
        int s = v;
        #pragma unroll
        for (int d = 1; d < 64; d <<= 1) {
            int t = __shfl_up(s, d, 64);
            if (lane >= d) s += t;
        }
        if (lane == 63) wsum[wid] = s;
        __syncthreads();
        if (threadIdx.x < 16) {
            int wv = wsum[threadIdx.x];
            #pragma unroll
            for (int d = 1; d < 16; d <<= 1) {
                int t = __shfl_up(wv, d, 16);
                if ((int)threadIdx.x >= d) wv += t;
            }
            wsum[threadIdx.x] = wv;
        }
        __syncthreads();
        int carry  = carry_s;
        int prefix = (wid > 0) ? wsum[wid - 1] : 0;
        int incl   = carry + prefix + s;
        if (i < n) row_ptr[i] = incl - v;   // exclusive
        __syncthreads();
        if (threadIdx.x == 1023) carry_s = incl;
        __syncthreads();
    }
    if (threadIdx.x == 0) row_ptr[n] = carry_s;
}

__global__ void cursor_kernel(const int* __restrict__ row_ptr, int* cursor,
                              int* sorted_src, int n) {
    int i = blockIdx.x * blockDim.x + threadIdx.x;
    if (i < n) {
        int rp = row_ptr[i];
        cursor[i] = rp + 1;     // slot rp reserved for self-loop
        sorted_src[rp] = i;
    }
}

__global__ void scatter_kernel(const int* __restrict__ eidx, int* cursor,
                               int* sorted_src, int n_edges) {
    int i = blockIdx.x * blockDim.x + threadIdx.x;
    if (i < n_edges) {
        int d = eidx[n_edges + i];
        int s = eidx[i];
        int pos = atomicAdd(&cursor[d], 1);
        sorted_src[pos] = s;
    }
}

// ---------------- Edge phase: one wave per dst node, online softmax ----------
// Lane layout: group g = lane>>4 handles edge (base+g); l0 = lane&15 holds
// (h, f) for f = l0*4 + {0..3}, h = 0..5  (24 values / lane).
__global__ __launch_bounds__(256) void edge_kernel(
    const _Float16* __restrict__ glr,     // [n][768]: gl = cols 0..383, gr = 384..767
    const int* __restrict__ row_ptr,
    const int* __restrict__ sorted_src,
    const float* __restrict__ att,        // [6][64]
    const float* __restrict__ bias,       // [64]
    float* __restrict__ out, int n_nodes)
{
    int wid  = threadIdx.x >> 6;
    int lane = threadIdx.x & 63;
    int node = blockIdx.x * 4 + wid;
    if (node >= n_nodes) return;
    int g  = lane >> 4;
    int l0 = lane & 15;

    float att_f[24], gr_f[24];
    const _Float16* grp = glr + (size_t)node * 768 + 384;
    #pragma unroll
    for (int h = 0; h < 6; h++) {
        f32x4  av = *(const f32x4*)(att + h * 64 + l0 * 4);
        half4_t gv = *(const half4_t*)(grp + h * 64 + l0 * 4);
        #pragma unroll
        for (int j = 0; j < 4; j++) {
            att_f[h * 4 + j] = av[j];
            gr_f[h * 4 + j]  = (float)gv[j];
        }
    }

    float m[6], s[6], acc[24];
    #pragma unroll
    for (int h = 0; h < 6; h++) { m[h] = -1e30f; s[h] = 0.f; }
    #pragma unroll
    for (int q = 0; q < 24; q++) acc[q] = 0.f;

    int rp = row_ptr[node], re = row_ptr[node + 1];
    for (int base = rp; base < re; base += 4) {
        int idx = base + g;
        bool active = idx < re;
        int srcn = active ? sorted_src[idx] : node;
        const _Float16* glp = glr + (size_t)srcn * 768;

        float glv[24];
        float e_h[6];
        #pragma unroll
        for (int h = 0; h < 6; h++) {
            half4_t gv = *(const half4_t*)(glp + h * 64 + l0 * 4);
            float p0 = 0.f;
            #pragma unroll
            for (int j = 0; j < 4; j++) {
                float xg = (float)gv[j];
                glv[h * 4 + j] = xg;
                float t = xg + gr_f[h * 4 + j];
                t = (t > 0.f) ? t : NEG_SLOPE * t;
                p0 += att_f[h * 4 + j] * t;
            }
            e_h[h] = p0;
        }
        // butterfly-reduce e over the 16-lane group
        #pragma unroll
        for (int d = 1; d < 16; d <<= 1)
            #pragma unroll
            for (int h = 0; h < 6; h++)
                e_h[h] += __shfl_xor(e_h[h], d, 64);

        if (active) {
            #pragma unroll
            for (int h = 0; h < 6; h++) {
                float e  = e_h[h];
                float mo = m[h];
                float mn = fmaxf(mo, e);
                float r  = __expf(mo - mn);
                float p  = __expf(e - mn);
                m[h] = mn;
                s[h] = s[h] * r + p;
                #pragma unroll
                for (int j = 0; j < 4; j++) {
                    int q = h * 4 + j;
                    acc[q] = acc[q] * r + p * glv[q];
                }
            }
        }
    }

    // merge the 4 group-partial softmax states (butterfly over xor 16, 32)
    #pragma unroll
    for (int d = 16; d < 64; d <<= 1) {
        #pragma unroll
        for (int h = 0; h < 6; h++) {
            float mo = __shfl_xor(m[h], d, 64);
            float so = __shfl_xor(s[h], d, 64);
            float mn = fmaxf(m[h], mo);
            float ra = __expf(m[h] - mn);
            float rb = __expf(mo - mn);
            float ns = s[h] * ra + so * rb;
            #pragma unroll
            for (int j = 0; j < 4; j++) {
                int q = h * 4 + j;
                float ao = __shfl_xor(acc[q], d, 64);
                acc[q] = acc[q] * ra + ao * rb;
            }
            m[h] = mn; s[h] = ns;
        }
    }

    if (g == 0) {
        float inv[6];
        #pragma unroll
        for (int h = 0; h < 6; h++) inv[h] = 1.0f / (s[h] + 1e-16f);
        f32x4 bv = *(const f32x4*)(bias + l0 * 4);
        f32x4 ov;
        #pragma unroll
        for (int j = 0; j < 4; j++) {
            float sum = 0.f;
            #pragma unroll
            for (int h = 0; h < 6; h++) sum += acc[h * 4 + j] * inv[h];
            float o = sum * (1.0f / 6.0f) + bv[j];
            o = (o > 0.f) ? SELU_SCALE * o
                          : SELU_SCALE * SELU_ALPHA * (__expf(o) - 1.0f);
            ov[j] = o;
        }
        *(f32x4*)(out + (size_t)node * 64 + l0 * 4) = ov;
    }
}

// ---------------- launch ----------------
extern "C" void kernel_launch(void* const* d_in, const int* in_sizes, int n_in,
                              void* d_out, int out_size, void* d_ws, size_t ws_size,
                              hipStream_t stream) {
    const float* x    = (const float*)d_in[0];
    const int*   eidx = (const int*)d_in[1];
    const float* Wl   = (const float*)d_in[2];
    const float* Wr   = (const float*)d_in[3];
    const float* att  = (const float*)d_in[4];
    const float* bias = (const float*)d_in[5];
    float* out = (float*)d_out;

    int n = in_sizes[0] / 64;        // nodes
    int E = in_sizes[1] / 2;         // edges (pre-self-loop)
    int Et = E + n;

    // workspace carve (256B aligned)
    char* w = (char*)d_ws;
    size_t off = 0;
    auto carve = [&](size_t bytes) {
        void* p = w + off;
        off = (off + bytes + 255) & ~(size_t)255;
        return p;
    };
    _Float16* glr      = (_Float16*)carve((size_t)n * 768 * sizeof(_Float16));
    int* count         = (int*)carve((size_t)n * sizeof(int));
    int* row_ptr       = (int*)carve((size_t)(n + 1) * sizeof(int));
    int* cursor        = (int*)carve((size_t)n * sizeof(int));
    int* sorted_src    = (int*)carve((size_t)Et * sizeof(int));
    (void)ws_size;

    int nb_n = (n + 255) / 256;
    int nb_e = (E + 255) / 256;

    hipLaunchKernelGGL(init_count_kernel, dim3(nb_n), dim3(256), 0, stream, count, n);
    hipLaunchKernelGGL(hist_kernel, dim3(nb_e), dim3(256), 0, stream, eidx, count, E);
    hipLaunchKernelGGL(scan_kernel, dim3(1), dim3(1024), 0, stream, count, row_ptr, n);
    hipLaunchKernelGGL(cursor_kernel, dim3(nb_n), dim3(256), 0, stream,
                       row_ptr, cursor, sorted_src, n);
    hipLaunchKernelGGL(scatter_kernel, dim3(nb_e), dim3(256), 0, stream,
                       eidx, cursor, sorted_src, E);
    hipLaunchKernelGGL(gemm_kernel, dim3((n + 63) / 64, 12), dim3(256), 0, stream,
                       x, Wl, Wr, glr, n);
    hipLaunchKernelGGL(edge_kernel, dim3((n + 3) / 4), dim3(256), 0, stream,
                       glr, row_ptr, sorted_src, att, bias, out, n);
}

// Round 2
// 287.697 us; speedup vs baseline: 1.3568x; 1.3568x over previous
//
#include <hip/hip_runtime.h>
#include <hip/hip_bf16.h>
#include <hip/hip_fp16.h>

typedef _Float16 half8 __attribute__((ext_vector_type(8)));
typedef _Float16 half4_t __attribute__((ext_vector_type(4)));
typedef _Float16 h2 __attribute__((ext_vector_type(2)));
typedef float f32x4 __attribute__((ext_vector_type(4)));
typedef unsigned int u32;

#define NEG_SLOPE 0.2f
#define SELU_SCALE 1.0507009873554805f
#define SELU_ALPHA 1.6732632423543772f

#if __has_builtin(__builtin_amdgcn_fdot2)
#define FDOT2(a, b, c) __builtin_amdgcn_fdot2((a), (b), (c), false)
#else
static __device__ inline float FDOT2(h2 a, h2 b, float c) {
    return c + (float)a[0] * (float)b[0] + (float)a[1] * (float)b[1];
}
#endif

static __device__ inline h2 h2max(h2 a, h2 b) {
#if __has_builtin(__builtin_elementwise_max)
    return __builtin_elementwise_max(a, b);
#else
    h2 r; r[0] = a[0] > b[0] ? a[0] : b[0]; r[1] = a[1] > b[1] ? a[1] : b[1]; return r;
#endif
}

// ---------------- GEMM: glr[n][c] = x[n][:] @ Wcat[:][c], c in [0,768)
// cols 0..383 = W_l (gl), 384..767 = W_r (gr). f16 out, fp32 MFMA accum.
// Block = 16 rows x 768 cols; x-tile staged in LDS once; W stays L2-hot.
__global__ __launch_bounds__(256) void gemm_kernel(
    const float* __restrict__ x, const float* __restrict__ Wl,
    const float* __restrict__ Wr, _Float16* __restrict__ glr, int n_nodes)
{
    __shared__ float xs[16 * 68];          // pad 64->68 to spread banks
    int row0 = blockIdx.x * 16;
    if (row0 >= n_nodes) return;

    {   // cooperative x-tile load: 1024 floats, 4 per thread (float4)
        int t = threadIdx.x;
        int r = t >> 4, c = (t & 15) * 4;
        int row = row0 + r;
        f32x4 v = (f32x4){0.f, 0.f, 0.f, 0.f};
        if (row < n_nodes) v = *(const f32x4*)(x + (size_t)row * 64 + c);
        *(f32x4*)(xs + r * 68 + c) = v;
    }
    __syncthreads();

    int wid  = threadIdx.x >> 6;
    int lane = threadIdx.x & 63;
    int l15  = lane & 15;
    int kb   = (lane >> 4) * 8;

    half8 a0, a1;
    #pragma unroll
    for (int j = 0; j < 8; j++) {
        a0[j] = (_Float16)xs[l15 * 68 + kb + j];
        a1[j] = (_Float16)xs[l15 * 68 + 32 + kb + j];
    }

    int colbase = wid * 192;               // each wave: 12 col-tiles of 16
    f32x4 acc[12];
    #pragma unroll
    for (int t = 0; t < 12; t++) acc[t] = (f32x4){0.f, 0.f, 0.f, 0.f};

    #pragma unroll
    for (int t = 0; t < 12; t++) {
        int col = colbase + t * 16 + l15;
        const float* wcol = (col < 384) ? (Wl + col) : (Wr + (col - 384));
        half8 b0, b1;
        #pragma unroll
        for (int j = 0; j < 8; j++) {
            b0[j] = (_Float16)wcol[(size_t)(kb + j) * 384];
            b1[j] = (_Float16)wcol[(size_t)(32 + kb + j) * 384];
        }
        acc[t] = __builtin_amdgcn_mfma_f32_16x16x32_f16(a0, b0, acc[t], 0, 0, 0);
        acc[t] = __builtin_amdgcn_mfma_f32_16x16x32_f16(a1, b1, acc[t], 0, 0, 0);
    }
    // C layout: col = lane&15, row = (lane>>4)*4 + r
    #pragma unroll
    for (int t = 0; t < 12; t++) {
        int col = colbase + t * 16 + l15;
        #pragma unroll
        for (int r = 0; r < 4; r++) {
            int row = row0 + (lane >> 4) * 4 + r;
            if (row < n_nodes)
                glr[(size_t)row * 768 + col] = (_Float16)acc[t][r];
        }
    }
}

// ---------------- CSR build ----------------
__global__ void init_count_kernel(int* count, int n) {
    int i = blockIdx.x * blockDim.x + threadIdx.x;
    if (i < n) count[i] = 1;   // self-loop pre-counted
}

__global__ void hist_kernel(const int* __restrict__ eidx, int* count, int n_edges) {
    int i = blockIdx.x * blockDim.x + threadIdx.x;
    if (i < n_edges) atomicAdd(&count[eidx[n_edges + i]], 1);  // dst row
}

// local scan of 1024-element chunks; writes exclusive-local into row_ptr,
// chunk totals into blksum
__global__ __launch_bounds__(256) void scan_local_kernel(
    const int* __restrict__ count, int* __restrict__ row_ptr,
    int* __restrict__ blksum, int n)
{
    __shared__ int ws[4];
    int blk = blockIdx.x, t = threadIdx.x;
    int base = blk * 1024 + t * 4;
    int a0 = (base + 0 < n) ? count[base + 0] : 0;
    int a1 = (base + 1 < n) ? count[base + 1] : 0;
    int a2 = (base + 2 < n) ? count[base + 2] : 0;
    int a3 = (base + 3 < n) ? count[base + 3] : 0;
    int tsum = a0 + a1 + a2 + a3;
    int lane = t & 63, wid = t >> 6;
    int s = tsum;
    #pragma unroll
    for (int d = 1; d < 64; d <<= 1) {
        int u = __shfl_up(s, d, 64);
        if (lane >= d) s += u;
    }
    if (lane == 63) ws[wid] = s;
    __syncthreads();
    int woff = 0;
    #pragma unroll
    for (int w = 0; w < 4; w++) if (w < wid) woff += ws[w];
    int excl = woff + s - tsum;            // exclusive prefix of this thread
    if (base + 0 < n) row_ptr[base + 0] = excl;
    if (base + 1 < n) row_ptr[base + 1] = excl + a0;
    if (base + 2 < n) row_ptr[base + 2] = excl + a0 + a1;
    if (base + 3 < n) row_ptr[base + 3] = excl + a0 + a1 + a2;
    if (t == 255) blksum[blk] = woff + s;  // chunk total
}

// exclusive scan of <=64 chunk totals (one wave); writes total to row_ptr[n]
__global__ __launch_bounds__(64) void scan_blk_kernel(
    int* __restrict__ blksum, int* __restrict__ row_ptr, int nblk, int n)
{
    int lane = threadIdx.x;
    int v = (lane < nblk) ? blksum[lane] : 0;
    int s = v;
    #pragma unroll
    for (int d = 1; d < 64; d <<= 1) {
        int u = __shfl_up(s, d, 64);
        if (lane >= d) s += u;
    }
    if (lane < nblk) blksum[lane] = s - v;  // exclusive
    if (lane == 63) row_ptr[n] = s;         // grand total = E + n
}

// finalize row_ptr (+chunk offset), init cursor, seed self-loops
__global__ void cursor_kernel(int* __restrict__ row_ptr,
                              const int* __restrict__ blksum,
                              int* __restrict__ cursor,
                              int* __restrict__ sorted_src, int n) {
    int i = blockIdx.x * blockDim.x + threadIdx.x;
    if (i < n) {
        int rp = row_ptr[i] + blksum[i >> 10];
        row_ptr[i] = rp;
        cursor[i] = rp + 1;     // slot rp reserved for self-loop
        sorted_src[rp] = i;
    }
}

__global__ void scatter_kernel(const int* __restrict__ eidx, int* cursor,
                               int* sorted_src, int n_edges) {
    int i = blockIdx.x * blockDim.x + threadIdx.x;
    if (i < n_edges) {
        int d = eidx[n_edges + i];
        int s = eidx[i];
        int pos = atomicAdd(&cursor[d], 1);
        sorted_src[pos] = s;
    }
}

// ---------------- Edge phase: one wave per dst node, online softmax ----------
// group g = lane>>4 handles edge (base+g); l0 = lane&15 holds (h, f) for
// f = l0*4 + {0..3}, h = 0..5. Packed-f16 logit path + f16 accumulator.
__global__ __launch_bounds__(256) void edge_kernel(
    const _Float16* __restrict__ glr,     // [n][768]: gl cols 0..383, gr 384..767
    const int* __restrict__ row_ptr,
    const int* __restrict__ sorted_src,
    const float* __restrict__ att,        // [6][64]
    const float* __restrict__ bias,       // [64]
    float* __restrict__ out, int n_nodes)
{
    int wid  = threadIdx.x >> 6;
    int lane = threadIdx.x & 63;
    int node = blockIdx.x * 4 + wid;
    if (node >= n_nodes) return;
    int g  = lane >> 4;
    int l0 = lane & 15;

    const _Float16 c02 = (_Float16)NEG_SLOPE;
    h2 c02v = (h2){c02, c02};

    h2 att_h[12], gr_h[12];
    const _Float16* grp = glr + (size_t)node * 768 + 384;
    #pragma unroll
    for (int h = 0; h < 6; h++) {
        f32x4 av = *(const f32x4*)(att + h * 64 + l0 * 4);
        att_h[2 * h]     = (h2){(_Float16)av[0], (_Float16)av[1]};
        att_h[2 * h + 1] = (h2){(_Float16)av[2], (_Float16)av[3]};
        half4_t gv = *(const half4_t*)(grp + h * 64 + l0 * 4);
        gr_h[2 * h]     = (h2){gv[0], gv[1]};
        gr_h[2 * h + 1] = (h2){gv[2], gv[3]};
    }

    float m[6], s[6];
    h2 acc[12];
    #pragma unroll
    for (int h = 0; h < 6; h++) { m[h] = -1e30f; s[h] = 0.f; }
    #pragma unroll
    for (int q = 0; q < 12; q++) acc[q] = (h2){(_Float16)0.f, (_Float16)0.f};

    int rp = row_ptr[node], re = row_ptr[node + 1];

    // preload first edge's gl fragment
    int idx0 = rp + g;
    int srcn = (idx0 < re) ? sorted_src[idx0] : node;
    half4_t gv[6];
    {
        const _Float16* glp = glr + (size_t)srcn * 768;
        #pragma unroll
        for (int h = 0; h < 6; h++)
            gv[h] = *(const half4_t*)(glp + h * 64 + l0 * 4);
    }

    for (int base = rp; base < re; base += 4) {
        bool active = (base + g) < re;

        // prefetch next iteration's gl fragment (register double-buffer)
        half4_t gvn[6];
        if (base + 4 < re) {
            int idxn = base + 4 + g;
            int srcn_n = (idxn < re) ? sorted_src[idxn] : node;
            const _Float16* glpn = glr + (size_t)srcn_n * 768;
            #pragma unroll
            for (int h = 0; h < 6; h++)
                gvn[h] = *(const half4_t*)(glpn + h * 64 + l0 * 4);
        } else {
            #pragma unroll
            for (int h = 0; h < 6; h++) gvn[h] = gv[h];
        }

        // packed-f16 logit partials, f32 dot accumulate
        float e[6];
        #pragma unroll
        for (int h = 0; h < 6; h++) {
            h2 g0 = (h2){gv[h][0], gv[h][1]};
            h2 g1 = (h2){gv[h][2], gv[h][3]};
            h2 t0 = g0 + gr_h[2 * h];
            h2 t1 = g1 + gr_h[2 * h + 1];
            h2 u0 = h2max(t0, t0 * c02v);    // leaky relu (slope>0)
            h2 u1 = h2max(t1, t1 * c02v);
            float ee = FDOT2(u0, att_h[2 * h], 0.f);
            e[h] = FDOT2(u1, att_h[2 * h + 1], ee);
        }
        // butterfly-reduce e over the 16-lane group
        #pragma unroll
        for (int d = 1; d < 16; d <<= 1)
            #pragma unroll
            for (int h = 0; h < 6; h++)
                e[h] += __shfl_xor(e[h], d, 64);

        if (active) {
            #pragma unroll
            for (int h = 0; h < 6; h++) {
                float mo = m[h];
                float mn = fmaxf(mo, e[h]);
                float r  = __expf(mo - mn);
                float p  = __expf(e[h] - mn);
                m[h] = mn;
                s[h] = s[h] * r + p;
                _Float16 rh = (_Float16)r, ph = (_Float16)p;
                h2 r2 = (h2){rh, rh}, p2 = (h2){ph, ph};
                acc[2 * h]     = acc[2 * h] * r2 + p2 * (h2){gv[h][0], gv[h][1]};
                acc[2 * h + 1] = acc[2 * h + 1] * r2 + p2 * (h2){gv[h][2], gv[h][3]};
            }
        }
        #pragma unroll
        for (int h = 0; h < 6; h++) gv[h] = gvn[h];
    }

    // merge the 4 group-partial softmax states (butterfly over xor 16, 32)
    #pragma unroll
    for (int d = 16; d < 64; d <<= 1) {
        #pragma unroll
        for (int h = 0; h < 6; h++) {
            float mo = __shfl_xor(m[h], d, 64);
            float so = __shfl_xor(s[h], d, 64);
            u32 a0u = __builtin_bit_cast(u32, acc[2 * h]);
            u32 a1u = __builtin_bit_cast(u32, acc[2 * h + 1]);
            h2 a0o = __builtin_bit_cast(h2, (u32)__shfl_xor((int)a0u, d, 64));
            h2 a1o = __builtin_bit_cast(h2, (u32)__shfl_xor((int)a1u, d, 64));
            float mn = fmaxf(m[h], mo);
            float ra = __expf(m[h] - mn);
            float rb = __expf(mo - mn);
            s[h] = s[h] * ra + so * rb;
            _Float16 rah = (_Float16)ra, rbh = (_Float16)rb;
            h2 ra2 = (h2){rah, rah}, rb2 = (h2){rbh, rbh};
            acc[2 * h]     = acc[2 * h] * ra2 + a0o * rb2;
            acc[2 * h + 1] = acc[2 * h + 1] * ra2 + a1o * rb2;
            m[h] = mn;
        }
    }

    if (g == 0) {
        float inv[6];
        #pragma unroll
        for (int h = 0; h < 6; h++) inv[h] = 1.0f / (s[h] + 1e-16f);
        f32x4 bv = *(const f32x4*)(bias + l0 * 4);
        f32x4 ov;
        #pragma unroll
        for (int j = 0; j < 4; j++) {
            float sum = 0.f;
            #pragma unroll
            for (int h = 0; h < 6; h++) {
                h2 a = acc[2 * h + (j >> 1)];
                sum += (float)a[j & 1] * inv[h];
            }
            float o = sum * (1.0f / 6.0f) + bv[j];
            o = (o > 0.f) ? SELU_SCALE * o
                          : SELU_SCALE * SELU_ALPHA * (__expf(o) - 1.0f);
            ov[j] = o;
        }
        *(f32x4*)(out + (size_t)node * 64 + l0 * 4) = ov;
    }
}

// ---------------- launch ----------------
extern "C" void kernel_launch(void* const* d_in, const int* in_sizes, int n_in,
                              void* d_out, int out_size, void* d_ws, size_t ws_size,
                              hipStream_t stream) {
    const float* x    = (const float*)d_in[0];
    const int*   eidx = (const int*)d_in[1];
    const float* Wl   = (const float*)d_in[2];
    const float* Wr   = (const float*)d_in[3];
    const float* att  = (const float*)d_in[4];
    const float* bias = (const float*)d_in[5];
    float* out = (float*)d_out;

    int n = in_sizes[0] / 64;        // nodes
    int E = in_sizes[1] / 2;         // edges (pre-self-loop)
    int Et = E + n;

    char* w = (char*)d_ws;
    size_t off = 0;
    auto carve = [&](size_t bytes) {
        void* p = w + off;
        off = (off + bytes + 255) & ~(size_t)255;
        return p;
    };
    _Float16* glr   = (_Float16*)carve((size_t)n * 768 * sizeof(_Float16));
    int* count      = (int*)carve((size_t)n * sizeof(int));
    int* row_ptr    = (int*)carve((size_t)(n + 1) * sizeof(int));
    int* cursor     = (int*)carve((size_t)n * sizeof(int));
    int* sorted_src = (int*)carve((size_t)Et * sizeof(int));
    int* blksum     = (int*)carve(64 * sizeof(int));
    (void)ws_size;

    int nb_n = (n + 255) / 256;
    int nb_e = (E + 255) / 256;
    int nblk = (n + 1023) / 1024;    // 49 for n=50000 (must be <= 64)

    hipLaunchKernelGGL(init_count_kernel, dim3(nb_n), dim3(256), 0, stream, count, n);
    hipLaunchKernelGGL(hist_kernel, dim3(nb_e), dim3(256), 0, stream, eidx, count, E);
    hipLaunchKernelGGL(scan_local_kernel, dim3(nblk), dim3(256), 0, stream,
                       count, row_ptr, blksum, n);
    hipLaunchKernelGGL(scan_blk_kernel, dim3(1), dim3(64), 0, stream,
                       blksum, row_ptr, nblk, n);
    hipLaunchKernelGGL(cursor_kernel, dim3(nb_n), dim3(256), 0, stream,
                       row_ptr, blksum, cursor, sorted_src, n);
    hipLaunchKernelGGL(scatter_kernel, dim3(nb_e), dim3(256), 0, stream,
                       eidx, cursor, sorted_src, E);
    hipLaunchKernelGGL(gemm_kernel, dim3((n + 15) / 16), dim3(256), 0, stream,
                       x, Wl, Wr, glr, n);
    hipLaunchKernelGGL(edge_kernel, dim3((n + 3) / 4), dim3(256), 0, stream,
                       glr, row_ptr, sorted_src, att, bias, out, n);
}